// Round 10
// baseline (274.407 us; speedup 1.0000x reference)
//
#include <hip/hip_runtime.h>
#include <hip/hip_bf16.h>
#include <math.h>

#define B_  2048
#define E_  64
#define H_  512
#define T_  20

typedef _Float16 half8 __attribute__((ext_vector_type(8)));
typedef __attribute__((ext_vector_type(4))) float f32x4;
typedef unsigned long long u64;

#define mf16(a, b, c) __builtin_amdgcn_mfma_f32_16x16x32_f16(a, b, c, 0, 0, 0)

__device__ __forceinline__ float sigmoidf_(float x) {
  return 1.0f / (1.0f + __expf(-x));
}
__device__ __forceinline__ float tanh_fast(float x) {
  float e = __expf(2.0f * x);
  return 1.0f - 2.0f / (e + 1.0f);
}

// ---------------------------------------------------------------------------
// Parallel stable counting sort + inverse perm + zero flag area.
// ---------------------------------------------------------------------------
__global__ __launch_bounds__(256) void k_setup(const int* __restrict__ data,
                                               const int* __restrict__ st,
                                               int* __restrict__ perm,
                                               int* __restrict__ iperm,
                                               int* __restrict__ Mt,
                                               int* __restrict__ bar) {
  __shared__ int lens[B_];
  __shared__ int hist[256][22];
  __shared__ int sub[16][22];
  __shared__ int subpre[16][22];
  __shared__ int cnt[32];
  __shared__ int offs[32];
  int tid = threadIdx.x;

  #pragma unroll
  for (int i = 0; i < 4; ++i) bar[tid * 4 + i] = 0;

  #pragma unroll
  for (int q = 0; q < 8; ++q) {
    int i = tid * 8 + q;
    lens[i] = st[data[i] * (T_ + 1) + T_];
  }
  #pragma unroll
  for (int L = 0; L < 22; ++L) hist[tid][L] = 0;
  #pragma unroll
  for (int q = 0; q < 8; ++q) hist[tid][lens[tid * 8 + q]]++;
  __syncthreads();

  for (int q = tid; q < 16 * 21; q += 256) {
    int g = q / 21, L = q % 21;
    int run = 0;
    for (int j = 0; j < 16; ++j) {
      int v = hist[g * 16 + j][L];
      hist[g * 16 + j][L] = run;
      run += v;
    }
    sub[g][L] = run;
  }
  __syncthreads();
  if (tid < 21) {
    int run = 0;
    for (int g = 0; g < 16; ++g) { subpre[g][tid] = run; run += sub[g][tid]; }
    cnt[tid] = run;
  }
  __syncthreads();
  if (tid <= 20) {
    int s = 0;
    for (int L = tid + 1; L <= 20; ++L) s += cnt[L];
    offs[tid] = s;
  }
  __syncthreads();
  if (tid < T_) Mt[tid] = offs[tid];
  if (tid >= T_ && tid < 32) Mt[tid] = 0;      // pad (Mnext reads Mt[20])

  int g = tid >> 4;
  #pragma unroll
  for (int q = 0; q < 8; ++q) {
    int i = tid * 8 + q;
    int L = lens[i];
    int rk = subpre[g][L] + hist[tid][L];
    hist[tid][L] += 1;
    perm[offs[L] + rk] = i;
  }
  __syncthreads();
  #pragma unroll
  for (int q = 0; q < 8; ++q) {
    int i = tid * 8 + q;
    iperm[perm[i]] = i;
  }
}

__global__ void k_schars(const int* __restrict__ data, const int* __restrict__ st,
                         const int* __restrict__ perm, int* __restrict__ schars_T) {
  int idx = blockIdx.x * 256 + threadIdx.x;
  if (idx >= B_ * T_) return;
  int t = idx >> 11;
  int j = idx & (B_ - 1);
  schars_T[idx] = st[data[perm[j]] * (T_ + 1) + t];
}

// W -> fp16 fragment-packed: Wp[(((cb*18+c)*4+wc)*3+g)*512 + l*8 + e]
__global__ void k_wconv(const float* __restrict__ W_ih, const float* __restrict__ W_hh,
                        _Float16* __restrict__ Wp) {
  int idx = blockIdx.x * 256 + threadIdx.x;
  if (idx >= 8 * 18 * 12 * 512) return;
  int e = idx & 7;
  int l = (idx >> 3) & 63;
  int rest = idx >> 9;
  int g = rest % 3;  rest /= 3;
  int w = rest & 3;  rest >>= 2;
  int c = rest % 18;
  int cb = rest / 18;
  int grow = g * H_ + cb * 64 + w * 16 + (l & 15);
  int k = c * 32 + (l >> 4) * 8 + e;
  float v = (k < E_) ? W_ih[grow * E_ + k] : W_hh[grow * H_ + (k - E_)];
  Wp[idx] = (_Float16)v;
}

__global__ void k_embconv(const float* __restrict__ emb, _Float16* __restrict__ embp) {
  int idx = blockIdx.x * 256 + threadIdx.x;
  if (idx >= 128 * E_) return;
  embp[idx] = (_Float16)emb[idx];
}

// ---------------------------------------------------------------------------
// Persistent GRU, K-split wave pairs.
// Block (rb=bid&31, cb=bid>>5): rows [rb*64,+64), h cols [cb*64,+64).
// 512 thr = 8 waves: wc = w&3 (16-col group), kh = w>>2 (K half).
//   kh=0: chunks 0..8  (emb k<64 + h cols 0..224)  -> 108 VGPR of W
//   kh=1: chunks 9..17 (h cols 224..512)           -> 108 VGPR of W
// Partials summed via LDS Rs (fp32), gates applied by kh0.
// Exchange: round-9 scheme (per-(rb,cb) flags, agent-scope u64 load/store,
// no fences). As[64][512] XOR-swizzled (16B slot ^ row&7 within a slice).
// ---------------------------------------------------------------------------
__global__ __launch_bounds__(512, 1) void k_gru(
    const int* __restrict__ Mt, const int* __restrict__ schars_T,
    const _Float16* __restrict__ embp, const _Float16* __restrict__ Wp,
    const float* __restrict__ b_ih, const float* __restrict__ b_hh,
    _Float16* __restrict__ hq0, _Float16* __restrict__ hq1,
    const int* __restrict__ iperm, float* __restrict__ out,
    int* __restrict__ flags) {
  __shared__ __attribute__((aligned(16))) _Float16 As[64][512];    // 64 KB
  __shared__ __attribute__((aligned(16))) float Rs[4][3][64][17];  // 55.5 KB

  int bid = blockIdx.x;
  int rb = bid & 31, cb = bid >> 5;
  int m0 = rb * 64;
  int tid = threadIdx.x;
  int w = tid >> 6, kh = w >> 2, wc = w & 3;
  int l = tid & 63, ln = l & 15, kc = l >> 4;
  int rS = tid >> 3, uS = tid & 7;     // staging: row 0..63, u64-unit 0..7

  // ---- W fragments (this wave's K-half) -> registers ----
  half8 wfr[27];
  #pragma unroll
  for (int f = 0; f < 9; ++f) {
    #pragma unroll
    for (int g = 0; g < 3; ++g) {
      int c = kh * 9 + f;
      wfr[f * 3 + g] = *(const half8*)(
          Wp + ((((size_t)cb * 18 + c) * 4 + wc) * 3 + g) * 512 + l * 8);
    }
  }

  int colg = cb * 64 + wc * 16 + ln;
  float br  = b_ih[colg] + b_hh[colg];
  float bz  = b_ih[H_ + colg] + b_hh[H_ + colg];
  float bnx = b_ih[2 * H_ + colg];
  float bnh = b_hh[2 * H_ + colg];

  float hreg[4][4];
  #pragma unroll
  for (int i = 0; i < 4; ++i)
    #pragma unroll
    for (int j = 0; j < 4; ++j) hreg[i][j] = 0.0f;

  int myflag = rb * 8 + cb;
  int Mnext = Mt[0];

// MFMA for h-chunk C (global chunk idx) against slice j in As (f = C - kh*9)
#define H_CHUNK(C, F)                                                          \
  {                                                                            \
    const int jsl = ((C) - 2) >> 1, c2 = ((C) - 2) & 1;                        \
    _Pragma("unroll")                                                          \
    for (int rf = 0; rf < 4; ++rf) {                                           \
      int r = rf * 16 + ln;                                                    \
      int slot = (c2 * 4 + kc) ^ (ln & 7);                                     \
      half8 af = *(const half8*)((const char*)As + r * 1024 + jsl * 128 + slot * 16); \
      accr[rf] = mf16(af, wfr[(F) * 3 + 0], accr[rf]);                         \
      accz[rf] = mf16(af, wfr[(F) * 3 + 1], accz[rf]);                         \
      accnh[rf] = mf16(af, wfr[(F) * 3 + 2], accnh[rf]);                       \
    }                                                                          \
  }

  #pragma unroll 1
  for (int t = 0; t < T_; ++t) {
    int M = Mnext;
    if (m0 >= M) break;
    Mnext = Mt[t + 1];
    const _Float16* hin  = (t & 1) ? hq1 : hq0;
    _Float16*       hout = (t & 1) ? hq0 : hq1;

    f32x4 accr[4], accz[4], accnx[4], accnh[4];
    #pragma unroll
    for (int i = 0; i < 4; ++i) {
      accr[i] = (f32x4){0.f, 0.f, 0.f, 0.f};
      accz[i] = (f32x4){0.f, 0.f, 0.f, 0.f};
      accnx[i] = (f32x4){0.f, 0.f, 0.f, 0.f};
      accnh[i] = (f32x4){0.f, 0.f, 0.f, 0.f};
    }

    // ---- emb chunks (kh0 only; c=0,1 -> n-gate goes to accnx) ----
    if (kh == 0) {
      #pragma unroll
      for (int rf = 0; rf < 4; ++rf) {
        int ch = schars_T[t * B_ + m0 + rf * 16 + ln];
        const _Float16* ep = embp + ch * E_ + kc * 8;
        half8 a0 = *(const half8*)ep;
        half8 a1 = *(const half8*)(ep + 32);
        accr[rf]  = mf16(a0, wfr[0], accr[rf]);
        accz[rf]  = mf16(a0, wfr[1], accz[rf]);
        accnx[rf] = mf16(a0, wfr[2], accnx[rf]);
        accr[rf]  = mf16(a1, wfr[3], accr[rf]);
        accz[rf]  = mf16(a1, wfr[4], accz[rf]);
        accnx[rf] = mf16(a1, wfr[5], accnx[rf]);
      }
    }

    if (t > 0) {
      // ---- own slice from As (written by our epilogue at t-1), pre-poll ----
      if (kh == 0) {
        #pragma unroll
        for (int j = 0; j < 4; ++j) {             // kh0 h-chunks: 2..8
          if (j == cb) {
            H_CHUNK(2 + 2 * j, 2 + 2 * j);
            if (3 + 2 * j <= 8) H_CHUNK(3 + 2 * j, 3 + 2 * j);
          }
        }
      } else {
        #pragma unroll
        for (int j = 3; j < 8; ++j) {             // kh1 h-chunks: 9..17
          if (j == cb) {
            if (2 + 2 * j >= 9) H_CHUNK(2 + 2 * j, 2 + 2 * j - 9);
            H_CHUNK(3 + 2 * j, 3 + 2 * j - 9);
          }
        }
      }

      // ---- poll partner flags (all threads; coalesced same-line loads) ----
      int* fb = flags + rb * 8;
      int ready = 0;
      while (!ready) {
        int acc = 1;
        #pragma unroll
        for (int jj = 0; jj < 7; ++jj) {
          int j = (cb + 1 + jj) & 7;
          int f = __hip_atomic_load(fb + j, __ATOMIC_RELAXED, __HIP_MEMORY_SCOPE_AGENT);
          acc &= (f >= t) ? 1 : 0;
        }
        ready = acc;
      }

      // ---- issue all staged loads (14 u64/thread, full MLP) ----
      u64 sb[8][2];
      #pragma unroll
      for (int j = 0; j < 8; ++j) {
        if (j != cb) {
          const u64* gp = (const u64*)(hin + (size_t)(m0 + rS) * H_) + j * 16;
          sb[j][0] = __hip_atomic_load((u64*)(gp + uS),
                                       __ATOMIC_RELAXED, __HIP_MEMORY_SCOPE_AGENT);
          sb[j][1] = __hip_atomic_load((u64*)(gp + uS + 8),
                                       __ATOMIC_RELAXED, __HIP_MEMORY_SCOPE_AGENT);
        }
      }

      // ---- consume slice by slice ----
      #pragma unroll
      for (int j = 0; j < 8; ++j) {
        if (j == cb) continue;                    // uniform per block
        #pragma unroll
        for (int i = 0; i < 2; ++i) {
          int u = uS + 8 * i;
          int slot = (u >> 1) ^ (rS & 7);
          *(u64*)((char*)As + rS * 1024 + j * 128 + slot * 16 + (u & 1) * 8) = sb[j][i];
        }
        __syncthreads();
        if (kh == 0) {
          if (2 + 2 * j <= 8) H_CHUNK(2 + 2 * j, 2 + 2 * j);
          if (3 + 2 * j <= 8) H_CHUNK(3 + 2 * j, 3 + 2 * j);
        } else {
          if (2 + 2 * j >= 9) H_CHUNK(2 + 2 * j, 2 + 2 * j - 9);
          if (3 + 2 * j >= 9) H_CHUNK(3 + 2 * j, 3 + 2 * j - 9);
        }
      }
    }

    // ---- cross-K reduction: kh1 partials -> LDS -> kh0 sums ----
    if (kh == 1) {
      #pragma unroll
      for (int rf = 0; rf < 4; ++rf)
        #pragma unroll
        for (int q = 0; q < 4; ++q) {
          int row = rf * 16 + kc * 4 + q;
          Rs[wc][0][row][ln] = accr[rf][q];
          Rs[wc][1][row][ln] = accz[rf][q];
          Rs[wc][2][row][ln] = accnh[rf][q];
        }
    }
    __syncthreads();

    // ---- epilogue (kh0): gates -> hreg + own slice fp16 into As ----
    if (kh == 0) {
      #pragma unroll
      for (int rf = 0; rf < 4; ++rf) {
        #pragma unroll
        for (int q = 0; q < 4; ++q) {
          int row_l = rf * 16 + kc * 4 + q;
          if (m0 + row_l < M) {
            float pr = accr[rf][q] + Rs[wc][0][row_l][ln] + br;
            float pz = accz[rf][q] + Rs[wc][1][row_l][ln] + bz;
            float xn = accnx[rf][q] + bnx;
            float hn = accnh[rf][q] + Rs[wc][2][row_l][ln] + bnh;
            float r_ = sigmoidf_(pr);
            float z_ = sigmoidf_(pz);
            float n_ = tanh_fast(xn + r_ * hn);
            hreg[rf][q] = (1.0f - z_) * n_ + z_ * hreg[rf][q];
          }
          int c = wc * 16 + ln;
          int slot = (c >> 3) ^ (row_l & 7);
          *(_Float16*)((char*)As + row_l * 1024 + cb * 128 + slot * 16 + (c & 7) * 2) =
              (_Float16)hreg[rf][q];
        }
      }
    }
    __syncthreads();

    // ---- coalesced device-scope store of own slice (all 512 threads) ----
    #pragma unroll
    for (int i = 0; i < 2; ++i) {
      int u = uS + 8 * i;
      int slot = (u >> 1) ^ (rS & 7);
      u64 v = *(const u64*)((const char*)As + rS * 1024 + cb * 128 + slot * 16 + (u & 1) * 8);
      __hip_atomic_store((u64*)(hout + (size_t)(m0 + rS) * H_) + cb * 16 + u, v,
                         __ATOMIC_RELAXED, __HIP_MEMORY_SCOPE_AGENT);
    }
    asm volatile("s_waitcnt vmcnt(0)" ::: "memory");
    __syncthreads();
    if (tid == 0)
      __hip_atomic_store(flags + myflag, t + 1, __ATOMIC_RELAXED, __HIP_MEMORY_SCOPE_AGENT);
  }
#undef H_CHUNK

  // ---- final state -> out[iperm[row]] (reference returns ht[perm]) ----
  if (kh == 0) {
    #pragma unroll
    for (int rf = 0; rf < 4; ++rf) {
      #pragma unroll
      for (int q = 0; q < 4; ++q) {
        int row = m0 + rf * 16 + kc * 4 + q;
        out[(size_t)iperm[row] * H_ + colg] = hreg[rf][q];
      }
    }
  }
}

extern "C" void kernel_launch(void* const* d_in, const int* in_sizes, int n_in,
                              void* d_out, int out_size, void* d_ws, size_t ws_size,
                              hipStream_t stream) {
  const int*   data = (const int*)d_in[0];
  const int*   st   = (const int*)d_in[1];
  const float* emb  = (const float*)d_in[2];
  const float* W_ih = (const float*)d_in[3];
  const float* W_hh = (const float*)d_in[4];
  const float* b_ih = (const float*)d_in[5];
  const float* b_hh = (const float*)d_in[6];
  float* out = (float*)d_out;

  // workspace (~6 MB)
  _Float16* hq0  = (_Float16*)d_ws;                 // B*H fp16
  _Float16* hq1  = hq0 + B_ * H_;                   // B*H fp16
  _Float16* Wp   = hq1 + B_ * H_;                   // 884736 fp16
  _Float16* embp = Wp + 8 * 18 * 12 * 512;          // 128*E fp16
  int* perm   = (int*)(embp + 128 * E_);
  int* iperm  = perm + B_;
  int* Mt     = iperm + B_;
  int* bar    = Mt + 32;                            // flags = first 256 ints
  int* schars = bar + 32 * 32;

  k_setup<<<1, 256, 0, stream>>>(data, st, perm, iperm, Mt, bar);
  k_schars<<<(B_ * T_ + 255) / 256, 256, 0, stream>>>(data, st, perm, schars);
  k_wconv<<<(8 * 18 * 12 * 512 + 255) / 256, 256, 0, stream>>>(W_ih, W_hh, Wp);
  k_embconv<<<(128 * E_ + 255) / 256, 256, 0, stream>>>(emb, embp);

  k_gru<<<dim3(256), dim3(512), 0, stream>>>(Mt, schars, embp, Wp, b_ih, b_hh,
                                             hq0, hq1, iperm, out, bar);
}

// Round 11
// 226.347 us; speedup vs baseline: 1.2123x; 1.2123x over previous
//
#include <hip/hip_runtime.h>
#include <hip/hip_bf16.h>
#include <math.h>

#define B_  2048
#define E_  64
#define H_  512
#define T_  20

typedef _Float16 half8 __attribute__((ext_vector_type(8)));
typedef __attribute__((ext_vector_type(4))) float f32x4;
typedef unsigned long long u64;

#define mf16(a, b, c) __builtin_amdgcn_mfma_f32_16x16x32_f16(a, b, c, 0, 0, 0)

__device__ __forceinline__ float sigmoidf_(float x) {
  return 1.0f / (1.0f + __expf(-x));
}
__device__ __forceinline__ float tanh_fast(float x) {
  float e = __expf(2.0f * x);
  return 1.0f - 2.0f / (e + 1.0f);
}

// ---------------------------------------------------------------------------
// Parallel stable counting sort + inverse perm + zero flag area (1024 ints).
// ---------------------------------------------------------------------------
__global__ __launch_bounds__(256) void k_setup(const int* __restrict__ data,
                                               const int* __restrict__ st,
                                               int* __restrict__ perm,
                                               int* __restrict__ iperm,
                                               int* __restrict__ Mt,
                                               int* __restrict__ flags) {
  __shared__ int lens[B_];
  __shared__ int hist[256][22];
  __shared__ int sub[16][22];
  __shared__ int subpre[16][22];
  __shared__ int cnt[32];
  __shared__ int offs[32];
  int tid = threadIdx.x;

  #pragma unroll
  for (int i = 0; i < 4; ++i) flags[tid * 4 + i] = 0;

  #pragma unroll
  for (int q = 0; q < 8; ++q) {
    int i = tid * 8 + q;
    lens[i] = st[data[i] * (T_ + 1) + T_];
  }
  #pragma unroll
  for (int L = 0; L < 22; ++L) hist[tid][L] = 0;
  #pragma unroll
  for (int q = 0; q < 8; ++q) hist[tid][lens[tid * 8 + q]]++;
  __syncthreads();

  for (int q = tid; q < 16 * 21; q += 256) {
    int g = q / 21, L = q % 21;
    int run = 0;
    for (int j = 0; j < 16; ++j) {
      int v = hist[g * 16 + j][L];
      hist[g * 16 + j][L] = run;
      run += v;
    }
    sub[g][L] = run;
  }
  __syncthreads();
  if (tid < 21) {
    int run = 0;
    for (int g = 0; g < 16; ++g) { subpre[g][tid] = run; run += sub[g][tid]; }
    cnt[tid] = run;
  }
  __syncthreads();
  if (tid <= 20) {
    int s = 0;
    for (int L = tid + 1; L <= 20; ++L) s += cnt[L];
    offs[tid] = s;
  }
  __syncthreads();
  if (tid < T_) Mt[tid] = offs[tid];
  if (tid >= T_ && tid < 32) Mt[tid] = 0;       // Mt[20] read by prefetch

  int g = tid >> 4;
  #pragma unroll
  for (int q = 0; q < 8; ++q) {
    int i = tid * 8 + q;
    int L = lens[i];
    int rk = subpre[g][L] + hist[tid][L];
    hist[tid][L] += 1;
    perm[offs[L] + rk] = i;
  }
  __syncthreads();
  #pragma unroll
  for (int q = 0; q < 8; ++q) {
    int i = tid * 8 + q;
    iperm[perm[i]] = i;
  }
}

__global__ void k_schars(const int* __restrict__ data, const int* __restrict__ st,
                         const int* __restrict__ perm, int* __restrict__ schars_T) {
  int idx = blockIdx.x * 256 + threadIdx.x;
  if (idx >= B_ * T_) return;
  int t = idx >> 11;
  int j = idx & (B_ - 1);
  schars_T[idx] = st[data[perm[j]] * (T_ + 1) + t];
}

// W_hh -> fp16 fragment-packed: Wp[((cb*16+c)*4+wc)*3+g][l*8+e]
// grow = g*512 + cb*64 + wc*16 + (l&15);  k = c*32 + (l>>4)*8 + e  (k in [0,512))
__global__ void k_wconv(const float* __restrict__ W_hh, _Float16* __restrict__ Wp) {
  int idx = blockIdx.x * 256 + threadIdx.x;
  if (idx >= 8 * 16 * 12 * 512) return;
  int e = idx & 7;
  int l = (idx >> 3) & 63;
  int rest = idx >> 9;
  int g = rest % 3;  rest /= 3;
  int wc = rest & 3; rest >>= 2;
  int c = rest % 16;
  int cb = rest / 16;
  int grow = g * H_ + cb * 64 + wc * 16 + (l & 15);
  int k = c * 32 + (l >> 4) * 8 + e;
  Wp[idx] = (_Float16)W_hh[grow * H_ + k];
}

// embW[c][g*512+col] = emb[c] . W_ih[g*512+col] + b_ih  (+ b_hh for r,z gates)
__global__ __launch_bounds__(256) void k_embw(const float* __restrict__ emb,
                                              const float* __restrict__ W_ih,
                                              const float* __restrict__ b_ih,
                                              const float* __restrict__ b_hh,
                                              float* __restrict__ embW) {
  int c = blockIdx.x;           // 128
  int tid = threadIdx.x;
  __shared__ float ev[64];
  if (tid < 64) ev[tid] = emb[c * E_ + tid];
  __syncthreads();
  for (int o = tid; o < 3 * H_; o += 256) {
    float s = b_ih[o];
    if (o < 2 * H_) s += b_hh[o];
    #pragma unroll
    for (int k = 0; k < E_; ++k) s = fmaf(ev[k], W_ih[o * E_ + k], s);
    embW[(size_t)c * (3 * H_) + o] = s;
  }
}

// ---------------------------------------------------------------------------
// Persistent GRU. Grid 512 = 64 rb x 8 cb; block 256 thr (4 waves = 4 wc);
// 32 rows x 64 hcols. 2 blocks/CU (launch_bounds(256,2), LDS ~70KB).
// W_hh chunks 0..12 in registers (156 VGPR), 13..15 in LDS Ws (36KB).
// x-side = embW table lookup in epilogue (no emb MFMA, no accnx).
// Exchange: per-(rb,cb) flags (one 64B line per rb), sc1 u64 load/store,
// vmcnt-drain before flag. Partners = 8 consecutive bids (deadlock-free
// even at 1 block/CU: cohorts complete in bid order).
// ---------------------------------------------------------------------------
__global__ __launch_bounds__(256, 2) void k_gru(
    const int* __restrict__ Mt, const int* __restrict__ schars_T,
    const float* __restrict__ embW, const _Float16* __restrict__ Wp,
    const float* __restrict__ b_hh,
    _Float16* __restrict__ hq0, _Float16* __restrict__ hq1,
    const int* __restrict__ iperm, float* __restrict__ out,
    int* __restrict__ flags) {
  __shared__ __attribute__((aligned(16))) _Float16 As[32][512];       // 32 KB
  __shared__ __attribute__((aligned(16))) _Float16 Ws[3 * 12 * 512];  // 36 KB

  int bid = blockIdx.x;
  int rb = bid >> 3, cb = bid & 7;
  int m0 = rb * 32;
  int tid = threadIdx.x;
  int w = tid >> 6;                    // wc: 16-col group
  int l = tid & 63, ln = l & 15, kc = l >> 4;
  int rS = tid >> 3, uS = tid & 7;     // staging: row 0..31, 16B slot 0..7

  // ---- Ws: chunks 13..15 (36*512 halfs) LDS copy, contiguous in Wp ----
  {
    const uint4* src = (const uint4*)(Wp + ((size_t)(cb * 16 + 13) * 12) * 512);
    uint4* dst = (uint4*)Ws;
    #pragma unroll
    for (int i = 0; i < 9; ++i) dst[tid + 256 * i] = src[tid + 256 * i];
  }

  // ---- W chunks 0..12 -> registers (39 frags = 156 VGPR) ----
  half8 wfr[39];
  #pragma unroll
  for (int c = 0; c < 13; ++c)
    #pragma unroll
    for (int g = 0; g < 3; ++g)
      wfr[c * 3 + g] = *(const half8*)(
          Wp + (((size_t)(cb * 16 + c) * 4 + w) * 3 + g) * 512 + l * 8);
  __syncthreads();   // Ws ready

  int colg = cb * 64 + w * 16 + ln;
  float bnh = b_hh[2 * H_ + colg];

  float hreg[2][4];
  #pragma unroll
  for (int i = 0; i < 2; ++i)
    #pragma unroll
    for (int j = 0; j < 4; ++j) hreg[i][j] = 0.0f;

  int Mnext = Mt[0];

// W fragment for (chunk c, gate g): regs for c<13, LDS for 13..15
#define WFRAG(c, g) ((c) < 13 ? wfr[(c) * 3 + (g)]                            \
    : *(const half8*)(Ws + (((c) - 13) * 12 + w * 3 + (g)) * 512 + l * 8))

// MFMA for h-chunk c (0..15): slice j=c>>1, half c2=c&1
#define H_CHUNK(c)                                                             \
  {                                                                            \
    const int jsl = (c) >> 1, c2 = (c) & 1;                                    \
    _Pragma("unroll")                                                          \
    for (int rf = 0; rf < 2; ++rf) {                                           \
      int r = rf * 16 + ln;                                                    \
      int slot = (c2 * 4 + kc) ^ (ln & 7);                                     \
      half8 af = *(const half8*)((const char*)As + r * 1024 + jsl * 128 + slot * 16); \
      accr[rf]  = mf16(af, WFRAG(c, 0), accr[rf]);                             \
      accz[rf]  = mf16(af, WFRAG(c, 1), accz[rf]);                             \
      accnh[rf] = mf16(af, WFRAG(c, 2), accnh[rf]);                            \
    }                                                                          \
  }

  #pragma unroll 1
  for (int t = 0; t < T_; ++t) {
    int M = Mnext;
    if (m0 >= M) break;
    Mnext = Mt[t + 1];
    const _Float16* hin  = (t & 1) ? hq1 : hq0;
    _Float16*       hout = (t & 1) ? hq0 : hq1;

    // early: this step's chars for the epilogue xw lookup
    int chv[2][4];
    #pragma unroll
    for (int rf = 0; rf < 2; ++rf)
      #pragma unroll
      for (int q = 0; q < 4; ++q)
        chv[rf][q] = schars_T[t * B_ + m0 + rf * 16 + kc * 4 + q];

    f32x4 accr[2], accz[2], accnh[2];
    #pragma unroll
    for (int i = 0; i < 2; ++i) {
      accr[i] = (f32x4){0.f, 0.f, 0.f, 0.f};
      accz[i] = (f32x4){0.f, 0.f, 0.f, 0.f};
      accnh[i] = (f32x4){0.f, 0.f, 0.f, 0.f};
    }

    if (t > 0) {
      // ---- own slice (in As from t-1 epilogue), before any waiting ----
      #pragma unroll
      for (int j = 0; j < 8; ++j)
        if (j == cb) { H_CHUNK(2 * j) H_CHUNK(2 * j + 1) }

      // ---- poll 7 partner flags (one 64B line) ----
      if (tid == 0) {
        int* fb = flags + rb * 16;
        int ready = 0;
        while (!ready) {
          int acc = 1;
          #pragma unroll
          for (int j = 0; j < 8; ++j) {
            if (j == cb) continue;
            int f = __hip_atomic_load(fb + j, __ATOMIC_RELAXED, __HIP_MEMORY_SCOPE_AGENT);
            acc &= (f >= t) ? 1 : 0;
          }
          ready = acc;
        }
      }
      __syncthreads();

      // ---- issue all partner staging loads (2 u64 per slice per thread) ----
      u64 sb[8][2];
      #pragma unroll
      for (int j = 0; j < 8; ++j) {
        if (j != cb) {
          const u64* gp = (const u64*)(hin + (size_t)(m0 + rS) * H_ + j * 64);
          sb[j][0] = __hip_atomic_load((u64*)(gp + uS * 2),
                                       __ATOMIC_RELAXED, __HIP_MEMORY_SCOPE_AGENT);
          sb[j][1] = __hip_atomic_load((u64*)(gp + uS * 2 + 1),
                                       __ATOMIC_RELAXED, __HIP_MEMORY_SCOPE_AGENT);
        }
      }

      // ---- consume slice by slice ----
      #pragma unroll
      for (int j = 0; j < 8; ++j) {
        if (j == cb) continue;
        {
          char* dp = (char*)As + rS * 1024 + j * 128 + ((uS ^ (rS & 7)) * 16);
          ((u64*)dp)[0] = sb[j][0];
          ((u64*)dp)[1] = sb[j][1];
        }
        __syncthreads();
        H_CHUNK(2 * j)
        H_CHUNK(2 * j + 1)
      }
    }

    // ---- epilogue: xw table + gates -> hreg; own slice fp16 -> As ----
    #pragma unroll
    for (int rf = 0; rf < 2; ++rf) {
      #pragma unroll
      for (int q = 0; q < 4; ++q) {
        int row_l = rf * 16 + kc * 4 + q;
        if (m0 + row_l < M) {
          const float* ew = embW + (size_t)chv[rf][q] * (3 * H_) + colg;
          float xwr = ew[0];
          float xwz = ew[H_];
          float xwn = ew[2 * H_];
          float r_ = sigmoidf_(accr[rf][q] + xwr);
          float z_ = sigmoidf_(accz[rf][q] + xwz);
          float n_ = tanh_fast(xwn + r_ * (accnh[rf][q] + bnh));
          hreg[rf][q] = (1.0f - z_) * n_ + z_ * hreg[rf][q];
        }
        int c = w * 16 + ln;
        int slot = (c >> 3) ^ (row_l & 7);
        *(_Float16*)((char*)As + row_l * 1024 + cb * 128 + slot * 16 + (c & 7) * 2) =
            (_Float16)hreg[rf][q];
      }
    }
    __syncthreads();

    // ---- coalesced sc1 store of own slice ----
    {
      const char* sp = (const char*)As + rS * 1024 + cb * 128 + ((uS ^ (rS & 7)) * 16);
      u64 v0 = ((const u64*)sp)[0];
      u64 v1 = ((const u64*)sp)[1];
      u64* gp = (u64*)(hout + (size_t)(m0 + rS) * H_ + cb * 64);
      __hip_atomic_store(gp + uS * 2, v0, __ATOMIC_RELAXED, __HIP_MEMORY_SCOPE_AGENT);
      __hip_atomic_store(gp + uS * 2 + 1, v1, __ATOMIC_RELAXED, __HIP_MEMORY_SCOPE_AGENT);
    }
    asm volatile("s_waitcnt vmcnt(0)" ::: "memory");
    __syncthreads();
    if (tid == 0)
      __hip_atomic_store(flags + rb * 16 + cb, t + 1,
                         __ATOMIC_RELAXED, __HIP_MEMORY_SCOPE_AGENT);
  }
#undef H_CHUNK
#undef WFRAG

  // ---- final state -> out[iperm[row]] (reference returns ht[perm]) ----
  #pragma unroll
  for (int rf = 0; rf < 2; ++rf) {
    #pragma unroll
    for (int q = 0; q < 4; ++q) {
      int row = m0 + rf * 16 + kc * 4 + q;
      out[(size_t)iperm[row] * H_ + colg] = hreg[rf][q];
    }
  }
}

extern "C" void kernel_launch(void* const* d_in, const int* in_sizes, int n_in,
                              void* d_out, int out_size, void* d_ws, size_t ws_size,
                              hipStream_t stream) {
  const int*   data = (const int*)d_in[0];
  const int*   st   = (const int*)d_in[1];
  const float* emb  = (const float*)d_in[2];
  const float* W_ih = (const float*)d_in[3];
  const float* W_hh = (const float*)d_in[4];
  const float* b_ih = (const float*)d_in[5];
  const float* b_hh = (const float*)d_in[6];
  float* out = (float*)d_out;

  // workspace (~7 MB)
  _Float16* hq0  = (_Float16*)d_ws;                 // B*H fp16 (2 MB)
  _Float16* hq1  = hq0 + B_ * H_;                   // 2 MB
  _Float16* Wp   = hq1 + B_ * H_;                   // 786432 halfs (1.5 MB)
  float*    embW = (float*)(Wp + 8 * 16 * 12 * 512);// 128*1536 fp32 (786 KB)
  int* perm   = (int*)(embW + 128 * 3 * H_);
  int* iperm  = perm + B_;
  int* Mt     = iperm + B_;
  int* flags  = Mt + 32;                            // 64 rb * 16 ints
  int* schars = flags + 64 * 16;

  k_setup<<<1, 256, 0, stream>>>(data, st, perm, iperm, Mt, flags);
  k_schars<<<(B_ * T_ + 255) / 256, 256, 0, stream>>>(data, st, perm, schars);
  k_wconv<<<(8 * 16 * 12 * 512 + 255) / 256, 256, 0, stream>>>(W_hh, Wp);
  k_embw<<<128, 256, 0, stream>>>(emb, W_ih, b_ih, b_hh, embW);

  k_gru<<<dim3(512), dim3(256), 0, stream>>>(Mt, schars, embW, Wp, b_hh,
                                             hq0, hq1, iperm, out, flags);
}